// Round 3
// baseline (278.038 us; speedup 1.0000x reference)
//
#include <hip/hip_runtime.h>

// DIST loss: out = sum_i sqrt((px_i-tx_i)^2 + (py_i-ty_i)^2) / (N+1)
// N = 16,777,216 points, float32 [N,2]. Streaming reduction, 268 MB read.
//
// Session history:
//  R1-R3: ~100 us kernel regardless of occupancy/pattern (~2.7 TB/s).
//  R5:    nontemporal loads -> 249.6 us total. Claim at the time:
//         allocating reads thrash the restore-resident L3 copy.
//  R6:    persistent double-buffered pipeline -> 246.9 (-2.7, ~noise).
//         "load continuity" FALSIFIED.
//  R7:    raw v_sqrt_f32 (no IEEE fixup) -> 245.8 (-1.1, noise).
//         "VALU-issue-bound" FALSIFIED.
//  R8 (this): discriminate the 3 remaining models by ablating NT
//         (plain allocating loads, nothing else changed):
//           A: L3-thrash (R5 claim)        -> regress to ~265-275
//           B: NT-blocks-L3-hits           -> improve to ~220-230
//           C: fill-writeback contention   -> unchanged ~246
//         Window arithmetic: 245.8 = 2x78 harness fills + partial
//         (60..77, not in top-5) + final + gaps. Partial sits 1.5-1.7x
//         above the 43us all-HBM floor and is insensitive to
//         structure/occupancy/VALU; only the cache-policy variable
//         remains untested in this structure.

typedef float floatx4 __attribute__((ext_vector_type(4)));

#define NBLOCKS 2048
#define NTHREADS 256
#define STAGE 4     // float4s per array per stage per thread
#define NSTAGES 4   // stages per block; NBLOCKS*NTHREADS*STAGE*NSTAGES = 8,388,608 = n4

__global__ __launch_bounds__(NTHREADS, 4)
void dist_partial_kernel(const floatx4* __restrict__ preds,
                         const floatx4* __restrict__ targets,
                         float* __restrict__ partials,
                         int n4) {
    const int span = STAGE * NSTAGES * NTHREADS;       // 4096 float4s per block
    const int base = blockIdx.x * span + threadIdx.x;

    float acc = 0.0f;

    if (base + span - NTHREADS < n4) {
        // Fast path: whole block tile in range.
        floatx4 pa[STAGE], ta[STAGE];   // current stage
        floatx4 pb[STAGE], tb[STAGE];   // next stage (prefetch)

        #pragma unroll
        for (int k = 0; k < STAGE; ++k) {
            pa[k] = preds[base + k * NTHREADS];
            ta[k] = targets[base + k * NTHREADS];
        }

        #pragma unroll
        for (int s = 0; s < NSTAGES; ++s) {
            if (s + 1 < NSTAGES) {
                const int nb = base + (s + 1) * STAGE * NTHREADS;
                #pragma unroll
                for (int k = 0; k < STAGE; ++k) {
                    pb[k] = preds[nb + k * NTHREADS];
                    tb[k] = targets[nb + k * NTHREADS];
                }
            }
            #pragma unroll
            for (int k = 0; k < STAGE; ++k) {
                float dx0 = pa[k].x - ta[k].x;
                float dy0 = pa[k].y - ta[k].y;
                float dx1 = pa[k].z - ta[k].z;
                float dy1 = pa[k].w - ta[k].w;
                acc += __builtin_amdgcn_sqrtf(dx0 * dx0 + dy0 * dy0);
                acc += __builtin_amdgcn_sqrtf(dx1 * dx1 + dy1 * dy1);
            }
            if (s + 1 < NSTAGES) {
                #pragma unroll
                for (int k = 0; k < STAGE; ++k) { pa[k] = pb[k]; ta[k] = tb[k]; }
            }
        }
    } else {
        // Tail path (not taken for N=16M, kept for generality).
        for (int s = 0; s < NSTAGES; ++s) {
            for (int k = 0; k < STAGE; ++k) {
                int i = base + (s * STAGE + k) * NTHREADS;
                if (i < n4) {
                    floatx4 p = preds[i];
                    floatx4 t = targets[i];
                    float dx0 = p.x - t.x;
                    float dy0 = p.y - t.y;
                    float dx1 = p.z - t.z;
                    float dy1 = p.w - t.w;
                    acc += __builtin_amdgcn_sqrtf(dx0 * dx0 + dy0 * dy0);
                    acc += __builtin_amdgcn_sqrtf(dx1 * dx1 + dy1 * dy1);
                }
            }
        }
    }

    // wave-64 tree reduce
    #pragma unroll
    for (int off = 32; off > 0; off >>= 1)
        acc += __shfl_down(acc, off, 64);

    __shared__ float wave_sums[NTHREADS / 64];
    int lane = threadIdx.x & 63;
    int wave = threadIdx.x >> 6;
    if (lane == 0) wave_sums[wave] = acc;
    __syncthreads();

    if (threadIdx.x == 0) {
        float s = 0.0f;
        #pragma unroll
        for (int w = 0; w < NTHREADS / 64; ++w) s += wave_sums[w];
        partials[blockIdx.x] = s;
    }
}

__global__ __launch_bounds__(1024)
void dist_final_kernel(const float* __restrict__ partials,
                       float* __restrict__ out,
                       int nblocks, float inv_np1) {
    int tid = threadIdx.x;
    float acc = 0.0f;
    for (int i = tid; i < nblocks; i += 1024) acc += partials[i];

    #pragma unroll
    for (int off = 32; off > 0; off >>= 1)
        acc += __shfl_down(acc, off, 64);

    __shared__ float wave_sums[16];
    int lane = tid & 63;
    int wave = tid >> 6;
    if (lane == 0) wave_sums[wave] = acc;
    __syncthreads();

    if (tid == 0) {
        float s = 0.0f;
        #pragma unroll
        for (int w = 0; w < 16; ++w) s += wave_sums[w];
        out[0] = s * inv_np1;
    }
}

extern "C" void kernel_launch(void* const* d_in, const int* in_sizes, int n_in,
                              void* d_out, int out_size, void* d_ws, size_t ws_size,
                              hipStream_t stream) {
    const floatx4* preds   = (const floatx4*)d_in[0];
    const floatx4* targets = (const floatx4*)d_in[1];
    float* partials = (float*)d_ws;
    float* out = (float*)d_out;

    int n_elems  = in_sizes[0];      // N*2 floats = 33,554,432
    int n_points = n_elems / 2;      // 16,777,216
    int n4       = n_elems / 4;      // 8,388,608 float4s

    // Reference divides by float32(n+1); (float)(n_points+1) rounds to 2^24
    // identically to jnp.asarray(n+1, float32).
    float inv_np1 = 1.0f / (float)(n_points + 1);

    dist_partial_kernel<<<NBLOCKS, NTHREADS, 0, stream>>>(preds, targets, partials, n4);
    dist_final_kernel<<<1, 1024, 0, stream>>>(partials, out, NBLOCKS, inv_np1);
}

// Round 4
// 273.348 us; speedup vs baseline: 1.0172x; 1.0172x over previous
//
#include <hip/hip_runtime.h>

// DIST loss: out = sum_i sqrt((px_i-tx_i)^2 + (py_i-ty_i)^2) / (N+1)
// N = 16,777,216 points, float32 [N,2]. Streaming reduction, 268 MB read.
//
// Session history:
//  R1-R3: ~100 us kernel regardless of occupancy/pattern (~2.7 TB/s).
//  R5:    nontemporal loads -> 249.6 total; partial ~70us.
//  R6:    reg double-buffer pipeline -> 246.9. "load continuity" null.
//  R7:    raw v_sqrt_f32 -> 245.8. "VALU-bound" null.
//  R8:    NT ablation -> 278 total; partial VISIBLE: 101us, VALUBusy 3.9%,
//         FETCH exactly half (L3 serves rest), hbm 1.3 TB/s. No pipe busy.
//         => LATENCY-BOUND (Little's law). VGPR-held loads pin in-flight
//         bytes at ~4-6 KB/CU (4 VGPR per 16B load * occupancy tradeoff);
//         need ~13+ KB/CU for 6.3 TB/s at ~540ns loaded latency.
//  R9 (this): break the VGPR wall with global_load_lds DMA staging.
//         Per-wave private 4-slot LDS ring, 2 gload_lds (1KB each) per
//         tile, counted s_waitcnt vmcnt(N) -- no barriers, no VGPR cost
//         for in-flight data. ~8KB/wave * ~16 waves/CU >> requirement.
//         Allocating policy (aux=0): latency-immune now, and worst-case
//         full-HBM 268MB @ 6.5 TB/s = 41us beats the 70us NT baseline.

typedef float floatx4 __attribute__((ext_vector_type(4)));

#define NBLOCKS    2048
#define NTHREADS   256
#define NWAVES     (NTHREADS / 64)       // 4
#define DEPTH      4                     // LDS ring slots per wave
#define WAVE_TILES 16                    // tiles/wave; 2048*4*16*64 = 8,388,608 = n4
#define SPAN       (NWAVES * WAVE_TILES * 64)   // float4s per block = 4096

#define WAITV(N) asm volatile("s_waitcnt vmcnt(" #N ")" ::: "memory")

typedef const __attribute__((address_space(1))) void gvoid;
typedef __attribute__((address_space(3))) void lvoid;

__global__ __launch_bounds__(NTHREADS, 4)
void dist_partial_kernel(const floatx4* __restrict__ preds,
                         const floatx4* __restrict__ targets,
                         float* __restrict__ partials,
                         int n4) {
    // Per-wave private staging: [wave][slot][lane]. 2 arrays * 4KB*DEPTH = 32 KB.
    __shared__ floatx4 lds_p[NWAVES][DEPTH][64];
    __shared__ floatx4 lds_t[NWAVES][DEPTH][64];

    const int wave = threadIdx.x >> 6;
    const int lane = threadIdx.x & 63;
    const int block_base = blockIdx.x * SPAN;
    // this thread's global float4 index for tile t is wbase + t*64
    const int wbase = block_base + wave * (WAVE_TILES * 64) + lane;

    float acc = 0.0f;

    if (block_base + SPAN <= n4) {
        // ---- prologue: fill the ring (DEPTH tiles, 2 loads each) ----
        #pragma unroll
        for (int t = 0; t < DEPTH; ++t) {
            __builtin_amdgcn_global_load_lds((gvoid*)&preds[wbase + t * 64],
                                             (lvoid*)&lds_p[wave][t][0], 16, 0, 0);
            __builtin_amdgcn_global_load_lds((gvoid*)&targets[wbase + t * 64],
                                             (lvoid*)&lds_t[wave][t][0], 16, 0, 0);
        }

        // ---- steady state: wait oldest tile, consume, refill slot ----
        #pragma unroll
        for (int t = 0; t < WAVE_TILES; ++t) {
            const int rem = WAVE_TILES - 1 - t;              // tiles in flight beyond current
            const int w   = 2 * (rem < DEPTH - 1 ? rem : DEPTH - 1);
            switch (w) {                                     // folds to one asm at compile time
                case 6: WAITV(6); break;
                case 4: WAITV(4); break;
                case 2: WAITV(2); break;
                default: WAITV(0); break;
            }
            __builtin_amdgcn_sched_barrier(0);               // keep LDS reads after the wait

            const int slot = t & (DEPTH - 1);
            floatx4 p  = lds_p[wave][slot][lane];
            floatx4 tt = lds_t[wave][slot][lane];

            float dx0 = p.x - tt.x;
            float dy0 = p.y - tt.y;
            float dx1 = p.z - tt.z;
            float dy1 = p.w - tt.w;
            acc += __builtin_amdgcn_sqrtf(dx0 * dx0 + dy0 * dy0);
            acc += __builtin_amdgcn_sqrtf(dx1 * dx1 + dy1 * dy1);

            // compiler fence: issue of the slot-reuse DMA must stay after the
            // ds_reads above (data already in VGPRs by the lgkmcnt wait the
            // compiler emits before the VALU uses).
            asm volatile("" ::: "memory");

            if (t + DEPTH < WAVE_TILES) {
                __builtin_amdgcn_global_load_lds((gvoid*)&preds[wbase + (t + DEPTH) * 64],
                                                 (lvoid*)&lds_p[wave][slot][0], 16, 0, 0);
                __builtin_amdgcn_global_load_lds((gvoid*)&targets[wbase + (t + DEPTH) * 64],
                                                 (lvoid*)&lds_t[wave][slot][0], 16, 0, 0);
            }
        }
    } else {
        // Tail path (not taken for N=16M, kept for generality).
        for (int t = 0; t < WAVE_TILES; ++t) {
            int i = wbase + t * 64;
            if (i < n4) {
                floatx4 p  = preds[i];
                floatx4 tt = targets[i];
                float dx0 = p.x - tt.x;
                float dy0 = p.y - tt.y;
                float dx1 = p.z - tt.z;
                float dy1 = p.w - tt.w;
                acc += __builtin_amdgcn_sqrtf(dx0 * dx0 + dy0 * dy0);
                acc += __builtin_amdgcn_sqrtf(dx1 * dx1 + dy1 * dy1);
            }
        }
    }

    // wave-64 tree reduce
    #pragma unroll
    for (int off = 32; off > 0; off >>= 1)
        acc += __shfl_down(acc, off, 64);

    __shared__ float wave_sums[NWAVES];
    if (lane == 0) wave_sums[wave] = acc;
    __syncthreads();

    if (threadIdx.x == 0) {
        float s = 0.0f;
        #pragma unroll
        for (int w = 0; w < NWAVES; ++w) s += wave_sums[w];
        partials[blockIdx.x] = s;
    }
}

__global__ __launch_bounds__(1024)
void dist_final_kernel(const float* __restrict__ partials,
                       float* __restrict__ out,
                       int nblocks, float inv_np1) {
    int tid = threadIdx.x;
    float acc = 0.0f;
    for (int i = tid; i < nblocks; i += 1024) acc += partials[i];

    #pragma unroll
    for (int off = 32; off > 0; off >>= 1)
        acc += __shfl_down(acc, off, 64);

    __shared__ float wave_sums[16];
    int lane = tid & 63;
    int wave = tid >> 6;
    if (lane == 0) wave_sums[wave] = acc;
    __syncthreads();

    if (tid == 0) {
        float s = 0.0f;
        #pragma unroll
        for (int w = 0; w < 16; ++w) s += wave_sums[w];
        out[0] = s * inv_np1;
    }
}

extern "C" void kernel_launch(void* const* d_in, const int* in_sizes, int n_in,
                              void* d_out, int out_size, void* d_ws, size_t ws_size,
                              hipStream_t stream) {
    const floatx4* preds   = (const floatx4*)d_in[0];
    const floatx4* targets = (const floatx4*)d_in[1];
    float* partials = (float*)d_ws;
    float* out = (float*)d_out;

    int n_elems  = in_sizes[0];      // N*2 floats = 33,554,432
    int n_points = n_elems / 2;      // 16,777,216
    int n4       = n_elems / 4;      // 8,388,608 float4s

    // Reference divides by float32(n+1); (float)(n_points+1) rounds to 2^24
    // identically to jnp.asarray(n+1, float32).
    float inv_np1 = 1.0f / (float)(n_points + 1);

    dist_partial_kernel<<<NBLOCKS, NTHREADS, 0, stream>>>(preds, targets, partials, n4);
    dist_final_kernel<<<1, 1024, 0, stream>>>(partials, out, NBLOCKS, inv_np1);
}

// Round 5
// 267.069 us; speedup vs baseline: 1.0411x; 1.0235x over previous
//
#include <hip/hip_runtime.h>

// DIST loss: out = sum_i sqrt((px_i-tx_i)^2 + (py_i-ty_i)^2) / (N+1)
// N = 16,777,216 points, float32 [N,2]. Streaming reduction, 268 MB read.
//
// Session history:
//  R1-R3: ~100 us kernel regardless of occupancy/pattern (~2.7 TB/s).
//  R5:    nontemporal loads -> 249.6 total; partial ~70us.
//  R6:    reg double-buffer pipeline -> 246.9. "load continuity" null.
//  R7:    raw v_sqrt_f32 -> 245.8 (best). "VALU-bound" null.
//  R8:    NT ablation (allocating) -> 278; partial 101us, VALUBusy 3.9%,
//         FETCH exactly half, hbm 1.3 TB/s. No pipe busy.
//  R9:    gload_lds DMA ring (allocating, counted vmcnt, ~100KB/CU in
//         flight) -> partial 99us == R8. LATENCY/CONCURRENCY MODEL
//         FALSIFIED. Evidence matrix {VGPR,DMA}x{NT,alloc}: only cache
//         POLICY ever moved the number (alloc ~101, NT ~70). Read path
//         is capped ~3.8-4 TB/s chip-wide (m13 copy ubench read
//         component ~3.1 TB/s is consistent).
//  R10 (this): revert to R7 structure (best) + ONE variable: per-array
//         cache policy. preds = allocating (134MB fits L3 256MB with no
//         self-eviction -> stable hits if L3 survives the harness
//         fills), targets = NT (never allocates -> never evicts preds).
//         R8's FETCH=half proves L3 can serve half the inputs; R8 was
//         slow because BOTH arrays competed for exactly-L3-sized space.
//         Win: partial ~55-60us (FETCH ~134MB). Null: ~70us == R7,
//         then declare roofline.

typedef float floatx4 __attribute__((ext_vector_type(4)));

#define NBLOCKS 2048
#define NTHREADS 256
#define STAGE 4     // float4s per array per stage per thread
#define NSTAGES 4   // stages per block; NBLOCKS*NTHREADS*STAGE*NSTAGES = 8,388,608 = n4

__global__ __launch_bounds__(NTHREADS, 4)
void dist_partial_kernel(const floatx4* __restrict__ preds,
                         const floatx4* __restrict__ targets,
                         float* __restrict__ partials,
                         int n4) {
    const int span = STAGE * NSTAGES * NTHREADS;       // 4096 float4s per block
    const int base = blockIdx.x * span + threadIdx.x;

    float acc = 0.0f;

    if (base + span - NTHREADS < n4) {
        // Fast path: whole block tile in range.
        floatx4 pa[STAGE], ta[STAGE];   // current stage
        floatx4 pb[STAGE], tb[STAGE];   // next stage (prefetch)

        #pragma unroll
        for (int k = 0; k < STAGE; ++k) {
            pa[k] = preds[base + k * NTHREADS];                              // allocating
            ta[k] = __builtin_nontemporal_load(&targets[base + k * NTHREADS]); // NT
        }

        #pragma unroll
        for (int s = 0; s < NSTAGES; ++s) {
            if (s + 1 < NSTAGES) {
                const int nb = base + (s + 1) * STAGE * NTHREADS;
                #pragma unroll
                for (int k = 0; k < STAGE; ++k) {
                    pb[k] = preds[nb + k * NTHREADS];                              // allocating
                    tb[k] = __builtin_nontemporal_load(&targets[nb + k * NTHREADS]); // NT
                }
            }
            #pragma unroll
            for (int k = 0; k < STAGE; ++k) {
                float dx0 = pa[k].x - ta[k].x;
                float dy0 = pa[k].y - ta[k].y;
                float dx1 = pa[k].z - ta[k].z;
                float dy1 = pa[k].w - ta[k].w;
                acc += __builtin_amdgcn_sqrtf(dx0 * dx0 + dy0 * dy0);
                acc += __builtin_amdgcn_sqrtf(dx1 * dx1 + dy1 * dy1);
            }
            if (s + 1 < NSTAGES) {
                #pragma unroll
                for (int k = 0; k < STAGE; ++k) { pa[k] = pb[k]; ta[k] = tb[k]; }
            }
        }
    } else {
        // Tail path (not taken for N=16M, kept for generality).
        for (int s = 0; s < NSTAGES; ++s) {
            for (int k = 0; k < STAGE; ++k) {
                int i = base + (s * STAGE + k) * NTHREADS;
                if (i < n4) {
                    floatx4 p = preds[i];
                    floatx4 t = targets[i];
                    float dx0 = p.x - t.x;
                    float dy0 = p.y - t.y;
                    float dx1 = p.z - t.z;
                    float dy1 = p.w - t.w;
                    acc += __builtin_amdgcn_sqrtf(dx0 * dx0 + dy0 * dy0);
                    acc += __builtin_amdgcn_sqrtf(dx1 * dx1 + dy1 * dy1);
                }
            }
        }
    }

    // wave-64 tree reduce
    #pragma unroll
    for (int off = 32; off > 0; off >>= 1)
        acc += __shfl_down(acc, off, 64);

    __shared__ float wave_sums[NTHREADS / 64];
    int lane = threadIdx.x & 63;
    int wave = threadIdx.x >> 6;
    if (lane == 0) wave_sums[wave] = acc;
    __syncthreads();

    if (threadIdx.x == 0) {
        float s = 0.0f;
        #pragma unroll
        for (int w = 0; w < NTHREADS / 64; ++w) s += wave_sums[w];
        partials[blockIdx.x] = s;
    }
}

__global__ __launch_bounds__(1024)
void dist_final_kernel(const float* __restrict__ partials,
                       float* __restrict__ out,
                       int nblocks, float inv_np1) {
    int tid = threadIdx.x;
    float acc = 0.0f;
    for (int i = tid; i < nblocks; i += 1024) acc += partials[i];

    #pragma unroll
    for (int off = 32; off > 0; off >>= 1)
        acc += __shfl_down(acc, off, 64);

    __shared__ float wave_sums[16];
    int lane = tid & 63;
    int wave = tid >> 6;
    if (lane == 0) wave_sums[wave] = acc;
    __syncthreads();

    if (tid == 0) {
        float s = 0.0f;
        #pragma unroll
        for (int w = 0; w < 16; ++w) s += wave_sums[w];
        out[0] = s * inv_np1;
    }
}

extern "C" void kernel_launch(void* const* d_in, const int* in_sizes, int n_in,
                              void* d_out, int out_size, void* d_ws, size_t ws_size,
                              hipStream_t stream) {
    const floatx4* preds   = (const floatx4*)d_in[0];
    const floatx4* targets = (const floatx4*)d_in[1];
    float* partials = (float*)d_ws;
    float* out = (float*)d_out;

    int n_elems  = in_sizes[0];      // N*2 floats = 33,554,432
    int n_points = n_elems / 2;      // 16,777,216
    int n4       = n_elems / 4;      // 8,388,608 float4s

    // Reference divides by float32(n+1); (float)(n_points+1) rounds to 2^24
    // identically to jnp.asarray(n+1, float32).
    float inv_np1 = 1.0f / (float)(n_points + 1);

    dist_partial_kernel<<<NBLOCKS, NTHREADS, 0, stream>>>(preds, targets, partials, n4);
    dist_final_kernel<<<1, 1024, 0, stream>>>(partials, out, NBLOCKS, inv_np1);
}

// Round 6
// 249.339 us; speedup vs baseline: 1.1151x; 1.0711x over previous
//
#include <hip/hip_runtime.h>

// DIST loss: out = sum_i sqrt((px_i-tx_i)^2 + (py_i-ty_i)^2) / (N+1)
// N = 16,777,216 points, float32 [N,2]. Streaming reduction, 268 MB read.
//
// Session history:
//  R1-R3: ~100 us kernel regardless of occupancy/pattern (~2.7 TB/s).
//  R5:    NT loads -> 249.6 total; partial ~70us.
//  R6:    reg double-buffer pipeline -> 246.9. "load continuity" null.
//  R7:    raw v_sqrt_f32 -> 245.8 (best total). "VALU-bound" null.
//  R8:    alloc-both -> partial 101us, VALUBusy 3.9%, FETCH exactly half,
//         hbm 1.3 TB/s. No pipe busy.
//  R9:    gload_lds DMA ring, ALLOC (aux=0) -> 99us == R8. Depth null
//         in the alloc regime (thrash serialization caps ~2.65 TB/s
//         regardless of outstanding count).
//  R10:   mixed policy (preds alloc / targets NT) -> partial 77.5us,
//         FETCH bit-identical to R8 (exactly one array from HBM).
//         Policy ranking: NT-both 70 > mixed 77.5 > alloc 101.
//  R11 (this): the UNMEASURED matrix cell: DMA depth x NT. R9 changed
//         two variables vs R7; its null only covers the alloc regime.
//         NT-regime numbers are consistent with latency-bound at the
//         VGPR-imposed 2-4 KB/CU in flight (-> 2.8-4 TB/s at ~350ns).
//         DMA ring holds ~128 KB/CU in flight at zero VGPR cost.
//         One variable vs R9: aux 0 -> 2 (CPol NT bit, gfx940+).
//         Win: partial 35-45us, total ~205-220. Null: read path has a
//         true ~3.8 TB/s ceiling -> declare roofline next round.

typedef float floatx4 __attribute__((ext_vector_type(4)));

#define NBLOCKS    2048
#define NTHREADS   256
#define NWAVES     (NTHREADS / 64)       // 4
#define DEPTH      4                     // LDS ring slots per wave
#define WAVE_TILES 16                    // tiles/wave; 2048*4*16*64 = 8,388,608 = n4
#define SPAN       (NWAVES * WAVE_TILES * 64)   // float4s per block = 4096

#define AUX_NT 2                         // CPol bit1 = NT (nontemporal) on gfx94x/95x

#define WAITV(N) asm volatile("s_waitcnt vmcnt(" #N ")" ::: "memory")

typedef const __attribute__((address_space(1))) void gvoid;
typedef __attribute__((address_space(3))) void lvoid;

__global__ __launch_bounds__(NTHREADS, 4)
void dist_partial_kernel(const floatx4* __restrict__ preds,
                         const floatx4* __restrict__ targets,
                         float* __restrict__ partials,
                         int n4) {
    // Per-wave private staging: [wave][slot][lane]. 2 arrays * 4KB*DEPTH = 32 KB.
    __shared__ floatx4 lds_p[NWAVES][DEPTH][64];
    __shared__ floatx4 lds_t[NWAVES][DEPTH][64];

    const int wave = threadIdx.x >> 6;
    const int lane = threadIdx.x & 63;
    const int block_base = blockIdx.x * SPAN;
    // this thread's global float4 index for tile t is wbase + t*64
    const int wbase = block_base + wave * (WAVE_TILES * 64) + lane;

    float acc = 0.0f;

    if (block_base + SPAN <= n4) {
        // ---- prologue: fill the ring (DEPTH tiles, 2 NT loads each) ----
        #pragma unroll
        for (int t = 0; t < DEPTH; ++t) {
            __builtin_amdgcn_global_load_lds((gvoid*)&preds[wbase + t * 64],
                                             (lvoid*)&lds_p[wave][t][0], 16, 0, AUX_NT);
            __builtin_amdgcn_global_load_lds((gvoid*)&targets[wbase + t * 64],
                                             (lvoid*)&lds_t[wave][t][0], 16, 0, AUX_NT);
        }

        // ---- steady state: wait oldest tile, consume, refill slot ----
        #pragma unroll
        for (int t = 0; t < WAVE_TILES; ++t) {
            const int rem = WAVE_TILES - 1 - t;              // tiles in flight beyond current
            const int w   = 2 * (rem < DEPTH - 1 ? rem : DEPTH - 1);
            switch (w) {                                     // folds to one asm at compile time
                case 6: WAITV(6); break;
                case 4: WAITV(4); break;
                case 2: WAITV(2); break;
                default: WAITV(0); break;
            }
            __builtin_amdgcn_sched_barrier(0);               // keep LDS reads after the wait

            const int slot = t & (DEPTH - 1);
            floatx4 p  = lds_p[wave][slot][lane];
            floatx4 tt = lds_t[wave][slot][lane];

            float dx0 = p.x - tt.x;
            float dy0 = p.y - tt.y;
            float dx1 = p.z - tt.z;
            float dy1 = p.w - tt.w;
            acc += __builtin_amdgcn_sqrtf(dx0 * dx0 + dy0 * dy0);
            acc += __builtin_amdgcn_sqrtf(dx1 * dx1 + dy1 * dy1);

            // compiler fence: slot-reuse DMA must not be hoisted above the
            // LDS reads (data reaches VGPRs via the compiler's lgkmcnt wait).
            asm volatile("" ::: "memory");

            if (t + DEPTH < WAVE_TILES) {
                __builtin_amdgcn_global_load_lds((gvoid*)&preds[wbase + (t + DEPTH) * 64],
                                                 (lvoid*)&lds_p[wave][slot][0], 16, 0, AUX_NT);
                __builtin_amdgcn_global_load_lds((gvoid*)&targets[wbase + (t + DEPTH) * 64],
                                                 (lvoid*)&lds_t[wave][slot][0], 16, 0, AUX_NT);
            }
        }
    } else {
        // Tail path (not taken for N=16M, kept for generality).
        for (int t = 0; t < WAVE_TILES; ++t) {
            int i = wbase + t * 64;
            if (i < n4) {
                floatx4 p  = preds[i];
                floatx4 tt = targets[i];
                float dx0 = p.x - tt.x;
                float dy0 = p.y - tt.y;
                float dx1 = p.z - tt.z;
                float dy1 = p.w - tt.w;
                acc += __builtin_amdgcn_sqrtf(dx0 * dx0 + dy0 * dy0);
                acc += __builtin_amdgcn_sqrtf(dx1 * dx1 + dy1 * dy1);
            }
        }
    }

    // wave-64 tree reduce
    #pragma unroll
    for (int off = 32; off > 0; off >>= 1)
        acc += __shfl_down(acc, off, 64);

    __shared__ float wave_sums[NWAVES];
    if (lane == 0) wave_sums[wave] = acc;
    __syncthreads();

    if (threadIdx.x == 0) {
        float s = 0.0f;
        #pragma unroll
        for (int w = 0; w < NWAVES; ++w) s += wave_sums[w];
        partials[blockIdx.x] = s;
    }
}

__global__ __launch_bounds__(1024)
void dist_final_kernel(const float* __restrict__ partials,
                       float* __restrict__ out,
                       int nblocks, float inv_np1) {
    int tid = threadIdx.x;
    float acc = 0.0f;
    for (int i = tid; i < nblocks; i += 1024) acc += partials[i];

    #pragma unroll
    for (int off = 32; off > 0; off >>= 1)
        acc += __shfl_down(acc, off, 64);

    __shared__ float wave_sums[16];
    int lane = tid & 63;
    int wave = tid >> 6;
    if (lane == 0) wave_sums[wave] = acc;
    __syncthreads();

    if (tid == 0) {
        float s = 0.0f;
        #pragma unroll
        for (int w = 0; w < 16; ++w) s += wave_sums[w];
        out[0] = s * inv_np1;
    }
}

extern "C" void kernel_launch(void* const* d_in, const int* in_sizes, int n_in,
                              void* d_out, int out_size, void* d_ws, size_t ws_size,
                              hipStream_t stream) {
    const floatx4* preds   = (const floatx4*)d_in[0];
    const floatx4* targets = (const floatx4*)d_in[1];
    float* partials = (float*)d_ws;
    float* out = (float*)d_out;

    int n_elems  = in_sizes[0];      // N*2 floats = 33,554,432
    int n_points = n_elems / 2;      // 16,777,216
    int n4       = n_elems / 4;      // 8,388,608 float4s

    // Reference divides by float32(n+1); (float)(n_points+1) rounds to 2^24
    // identically to jnp.asarray(n+1, float32).
    float inv_np1 = 1.0f / (float)(n_points + 1);

    dist_partial_kernel<<<NBLOCKS, NTHREADS, 0, stream>>>(preds, targets, partials, n4);
    dist_final_kernel<<<1, 1024, 0, stream>>>(partials, out, NBLOCKS, inv_np1);
}

// Round 7
// 248.698 us; speedup vs baseline: 1.1180x; 1.0026x over previous
//
#include <hip/hip_runtime.h>

// DIST loss: out = sum_i sqrt((px_i-tx_i)^2 + (py_i-ty_i)^2) / (N+1)
// N = 16,777,216 points, float32 [N,2]. Streaming reduction, 268 MB read.
//
// Session history (partial-kernel us unless noted):
//  R1-R3: ~100 regardless of occupancy/pattern (~2.7 TB/s).
//  R5:    NT loads -> total 249.6; partial ~70.
//  R6:    reg double-buffer -> 246.9 total. "load continuity" null.
//  R7:    raw v_sqrt_f32 -> 245.8 total (BEST). "VALU-bound" null.
//  R8:    alloc-both -> 101. VALUBusy 3.9%, FETCH exactly half, no pipe busy.
//  R9:    DMA ring alloc -> 99. Depth null (alloc regime).
//  R10:   mixed alloc/NT -> 77.5. FETCH bit-identical to R8.
//  R11:   DMA ring NT (~128KB/CU in flight) -> ~70 == VGPR NT.
//         CONCURRENCY FALSIFIED in both regimes (128KB/CU @ 3.8TB/s would
//         imply 8.6us latency -> it's a throughput cap on the read path).
//         Matrix {VGPR,DMA}x{alloc,NT} closed; only POLICY ever moved it:
//         alloc 101 > mixed 77.5 > NT 70. System copyBuffer reads at
//         1.7 TB/s in-window -- slower than us.
//  R12 (this): last untested axis: full cache-scope bits. gfx95x CPol
//         has sc0/sc1/nt; "sc0 nt sc1" = system-scope streaming, distinct
//         from plain nt. Inline-asm global_load_dwordx4 with all three
//         bits, R5/R7 geometry, single vmcnt(0) + sched_barrier fence
//         (rule #18). Outcomes pre-committed:
//           (a) streaming path: partial 45-55, total ~225-235
//           (b) forced-HBM for L3-resident half: total 265-280
//           (c) null ~246-250
//         On (b)/(c): revert to best and declare roofline next round.

typedef float floatx4 __attribute__((ext_vector_type(4)));

#define NBLOCKS 4096
#define NTHREADS 256
#define UNROLL 8   // float4s per thread per array; NBLOCKS*NTHREADS*UNROLL = 8,388,608 = n4

__global__ __launch_bounds__(NTHREADS, 2)
void dist_partial_kernel(const floatx4* __restrict__ preds,
                         const floatx4* __restrict__ targets,
                         float* __restrict__ partials,
                         int n4) {
    const int tile_base = blockIdx.x * (UNROLL * NTHREADS) + threadIdx.x;

    float acc = 0.0f;

    if (tile_base + (UNROLL - 1) * NTHREADS < n4) {
        floatx4 p[UNROLL], t[UNROLL];
        // System-scope streaming loads: sc0 + sc1 + nt.
        #pragma unroll
        for (int k = 0; k < UNROLL; ++k)
            asm volatile("global_load_dwordx4 %0, %1, off sc0 nt sc1"
                         : "=&v"(p[k])
                         : "v"(&preds[tile_base + k * NTHREADS]));
        #pragma unroll
        for (int k = 0; k < UNROLL; ++k)
            asm volatile("global_load_dwordx4 %0, %1, off sc0 nt sc1"
                         : "=&v"(t[k])
                         : "v"(&targets[tile_base + k * NTHREADS]));

        // Inline-asm loads are invisible to the compiler's vmcnt tracking:
        // drain explicitly, then full scheduling fence so no consumer is
        // placed above the wait (rule #18 analog for vmcnt).
        asm volatile("s_waitcnt vmcnt(0)" ::: "memory");
        __builtin_amdgcn_sched_barrier(0);

        #pragma unroll
        for (int k = 0; k < UNROLL; ++k) {
            float dx0 = p[k].x - t[k].x;
            float dy0 = p[k].y - t[k].y;
            float dx1 = p[k].z - t[k].z;
            float dy1 = p[k].w - t[k].w;
            acc += __builtin_amdgcn_sqrtf(dx0 * dx0 + dy0 * dy0);
            acc += __builtin_amdgcn_sqrtf(dx1 * dx1 + dy1 * dy1);
        }
    } else {
        // Tail path (not taken for N=16M, kept for generality).
        for (int k = 0; k < UNROLL; ++k) {
            int i = tile_base + k * NTHREADS;
            if (i < n4) {
                floatx4 p = preds[i];
                floatx4 t = targets[i];
                float dx0 = p.x - t.x;
                float dy0 = p.y - t.y;
                float dx1 = p.z - t.z;
                float dy1 = p.w - t.w;
                acc += __builtin_amdgcn_sqrtf(dx0 * dx0 + dy0 * dy0);
                acc += __builtin_amdgcn_sqrtf(dx1 * dx1 + dy1 * dy1);
            }
        }
    }

    // wave-64 tree reduce
    #pragma unroll
    for (int off = 32; off > 0; off >>= 1)
        acc += __shfl_down(acc, off, 64);

    __shared__ float wave_sums[NTHREADS / 64];
    int lane = threadIdx.x & 63;
    int wave = threadIdx.x >> 6;
    if (lane == 0) wave_sums[wave] = acc;
    __syncthreads();

    if (threadIdx.x == 0) {
        float s = 0.0f;
        #pragma unroll
        for (int w = 0; w < NTHREADS / 64; ++w) s += wave_sums[w];
        partials[blockIdx.x] = s;
    }
}

__global__ __launch_bounds__(1024)
void dist_final_kernel(const float* __restrict__ partials,
                       float* __restrict__ out,
                       int nblocks, float inv_np1) {
    int tid = threadIdx.x;
    float acc = 0.0f;
    for (int i = tid; i < nblocks; i += 1024) acc += partials[i];

    #pragma unroll
    for (int off = 32; off > 0; off >>= 1)
        acc += __shfl_down(acc, off, 64);

    __shared__ float wave_sums[16];
    int lane = tid & 63;
    int wave = tid >> 6;
    if (lane == 0) wave_sums[wave] = acc;
    __syncthreads();

    if (tid == 0) {
        float s = 0.0f;
        #pragma unroll
        for (int w = 0; w < 16; ++w) s += wave_sums[w];
        out[0] = s * inv_np1;
    }
}

extern "C" void kernel_launch(void* const* d_in, const int* in_sizes, int n_in,
                              void* d_out, int out_size, void* d_ws, size_t ws_size,
                              hipStream_t stream) {
    const floatx4* preds   = (const floatx4*)d_in[0];
    const floatx4* targets = (const floatx4*)d_in[1];
    float* partials = (float*)d_ws;
    float* out = (float*)d_out;

    int n_elems  = in_sizes[0];      // N*2 floats = 33,554,432
    int n_points = n_elems / 2;      // 16,777,216
    int n4       = n_elems / 4;      // 8,388,608 float4s

    // Reference divides by float32(n+1); (float)(n_points+1) rounds to 2^24
    // identically to jnp.asarray(n+1, float32).
    float inv_np1 = 1.0f / (float)(n_points + 1);

    dist_partial_kernel<<<NBLOCKS, NTHREADS, 0, stream>>>(preds, targets, partials, n4);
    dist_final_kernel<<<1, 1024, 0, stream>>>(partials, out, NBLOCKS, inv_np1);
}